// Round 10
// baseline (818.935 us; speedup 1.0000x reference)
//
#include <hip/hip_runtime.h>

// SWA non-overlapping window MHA, MI355X gfx950.
// K1 convert fp32->bf16 (x, w_in, w_out)
// K2 QKV GEMM [32768x1536x512]: 256x256xBK32 dbuf-2 (64KiB LDS, 2 blocks/CU)
// K3 attention per (window, head) -> ctx bf16 [M][512]
// K4 out-proj GEMM [32768x512x512] + bias -> fp32 d_out (same template)

typedef __bf16 bf16x8 __attribute__((ext_vector_type(8)));
typedef float  f32x4  __attribute__((ext_vector_type(4)));

#define MFMA16(a, b, c) __builtin_amdgcn_mfma_f32_16x16x32_bf16((a), (b), (c), 0, 0, 0)
#define VMCNT_(n) asm volatile("s_waitcnt vmcnt(" #n ")" ::: "memory")
#define VMCNT(n) VMCNT_(n)
#define LGKM0() asm volatile("s_waitcnt lgkmcnt(0)" ::: "memory")

__device__ __forceinline__ void gload_lds16(const __bf16* g, void* l) {
    __builtin_amdgcn_global_load_lds(
        (const __attribute__((address_space(1))) unsigned int*)g,
        (__attribute__((address_space(3))) unsigned int*)l, 16, 0, 0);
}

// ---------------- K1: fp32 -> bf16 conversion ----------------
__device__ __forceinline__ void cvt8(const float* __restrict__ s,
                                     __bf16* __restrict__ d, long i) {
    const float4* s4 = reinterpret_cast<const float4*>(s);
    float4 a = s4[2 * i], b = s4[2 * i + 1];
    bf16x8 v;
    v[0] = (__bf16)a.x; v[1] = (__bf16)a.y; v[2] = (__bf16)a.z; v[3] = (__bf16)a.w;
    v[4] = (__bf16)b.x; v[5] = (__bf16)b.y; v[6] = (__bf16)b.z; v[7] = (__bf16)b.w;
    *reinterpret_cast<bf16x8*>(d + 8 * i) = v;
}

__global__ void convert_k(const float* __restrict__ x,
                          const float* __restrict__ w_in,
                          const float* __restrict__ w_out,
                          __bf16* __restrict__ x_bf,
                          __bf16* __restrict__ w_in_bf,
                          __bf16* __restrict__ w_out_bf)
{
    long i0 = (long)blockIdx.x * blockDim.x + threadIdx.x;
    long stride = (long)gridDim.x * blockDim.x;
    for (long i = i0; i < 16777216 / 8; i += stride) cvt8(x, x_bf, i);
    for (long i = i0; i < 786432 / 8;   i += stride) cvt8(w_in, w_in_bf, i);
    for (long i = i0; i < 262144 / 8;   i += stride) cvt8(w_out, w_out_bf, i);
}

// ---------------- K2/K4: 256x256xBK32 GEMM, dbuf-2, 2 blocks/CU ----------------
// LDS 64 KiB: A bufs at 0/16K, B bufs at 32K/48K; [256 rows][64 B] per buf.
// 4-slot swizzle (R7-verified): store chunk (tid&3)^((srow>>1)&3), read
// slot hi^((lrow>>1)&3). One vmcnt(0)+lgkm+barrier per K-tile; the drain
// stall is covered by the co-resident block (2/CU) being phase-offset.
// Epilogue: direct scalar stores (dense block footprint -> L2 write-combines).
template<int EPI, int NN>
__global__ __launch_bounds__(512, 4)
void gemm256(const __bf16* __restrict__ A,
             const __bf16* __restrict__ Bw,
             const float* __restrict__ bias,
             void* __restrict__ Cq,
             __bf16* __restrict__ vT)
{
    __shared__ __align__(16) char smem[65536];

    const int nwg = gridDim.x;
    const int chunk = nwg >> 3;                       // nwg % 8 == 0
    const int bid = blockIdx.x;
    const int wg = (bid & 7) * chunk + (bid >> 3);    // XCD-contiguous chunks
    const int nidx = wg % NN;
    const int midx = wg / NN;
    const long mbase = (long)midx * 256;
    const int colbase = nidx * 256;

    const int tid = threadIdx.x;
    const int w = tid >> 6, lane = tid & 63;
    const int lrow = lane & 15, hi = lane >> 4;
    const int wm = w >> 2, wn = w & 3;                // wave tile 128x64

    // staging: srow = tid>>2 covers 128 rows/gload (2 gloads per operand);
    // 16B k-chunk pre-swizzled so LDS[row][s] = global chunk s^((row>>1)&3)
    const int srow = tid >> 2;
    const int kchunk = (tid & 3) ^ ((srow >> 1) & 3);
    const __bf16* PA = A  + (mbase + srow) * 512 + kchunk * 8;
    const __bf16* PB = Bw + ((long)colbase + srow) * 512 + kchunk * 8;
    // read-side: slot = hi ^ ((lrow>>1)&3) (rows are 16-aligned per frag)
    const int rd16 = (hi ^ ((lrow >> 1) & 3)) << 4;

    auto stage = [&](int t) {                         // 4 gload16/thread = 1 K-tile
        char* Ab = smem + (t & 1) * 16384;
        char* Bb = smem + 32768 + (t & 1) * 16384;
        const int ko = t * 32;
        gload_lds16(PA + ko,             Ab + w * 1024);
        gload_lds16(PA + 128 * 512 + ko, Ab + 8192 + w * 1024);
        gload_lds16(PB + ko,             Bb + w * 1024);
        gload_lds16(PB + 128 * 512 + ko, Bb + 8192 + w * 1024);
    };

    f32x4 acc[8][4];
    #pragma unroll
    for (int rt = 0; rt < 8; ++rt)
        #pragma unroll
        for (int ct = 0; ct < 4; ++ct) acc[rt][ct] = (f32x4){0.f, 0.f, 0.f, 0.f};

    stage(0);

    #pragma unroll 1
    for (int t = 0; t < 16; ++t) {
        VMCNT(0);                                     // tile t landed
        LGKM0();                                      // my reads of buf t&1 done
        __builtin_amdgcn_s_barrier();                 // all waves done with buf t&1
        if (t < 15) stage(t + 1);
        const char* Ab = smem + (t & 1) * 16384;
        const char* Bb = smem + 32768 + (t & 1) * 16384;
        bf16x8 af[8], bfr[4];
        #pragma unroll
        for (int i = 0; i < 8; ++i)
            af[i] = *reinterpret_cast<const bf16x8*>(
                Ab + (128 * wm + 16 * i + lrow) * 64 + rd16);
        #pragma unroll
        for (int ct = 0; ct < 4; ++ct)
            bfr[ct] = *reinterpret_cast<const bf16x8*>(
                Bb + (64 * wn + 16 * ct + lrow) * 64 + rd16);
        __builtin_amdgcn_s_setprio(1);
        #pragma unroll
        for (int i = 0; i < 8; ++i)
            #pragma unroll
            for (int ct = 0; ct < 4; ++ct)
                acc[i][ct] = MFMA16(af[i], bfr[ct], acc[i][ct]);
        __builtin_amdgcn_s_setprio(0);
    }

    // ---- epilogue: direct scalar stores (dense per-block footprint) ----
    if (EPI == 0) {
        if (colbase < 1024) {
            const float scale = (colbase < 512) ? 0.125f : 1.0f;
            __bf16* qk = (__bf16*)Cq;
            #pragma unroll
            for (int ct = 0; ct < 4; ++ct) {
                int colg = colbase + 64 * wn + 16 * ct + lrow;
                float b = bias[colg];
                #pragma unroll
                for (int rt = 0; rt < 8; ++rt) {
                    long row = mbase + 128 * wm + 16 * rt + 4 * hi;
                    #pragma unroll
                    for (int r = 0; r < 4; ++r)
                        qk[(row + r) * 1024 + colg] = (__bf16)((acc[rt][ct][r] + b) * scale);
                }
            }
        } else {
            // v -> vT[win][h][d][tok]
            #pragma unroll
            for (int ct = 0; ct < 4; ++ct) {
                int colg = colbase + 64 * wn + 16 * ct + lrow;
                float b = bias[colg];
                int e2 = colg - 1024;
                int h = e2 >> 6, d = e2 & 63;
                #pragma unroll
                for (int rt = 0; rt < 8; ++rt) {
                    long row = mbase + 128 * wm + 16 * rt + 4 * hi;
                    #pragma unroll
                    for (int r = 0; r < 4; ++r) {
                        long rr = row + r;
                        int win = (int)(rr >> 7), tok = (int)(rr & 127);
                        vT[(((long)win * 8 + h) * 64 + d) * 128 + tok] =
                            (__bf16)(acc[rt][ct][r] + b);
                    }
                }
            }
        }
    } else {
        float* outp = (float*)Cq;
        #pragma unroll
        for (int ct = 0; ct < 4; ++ct) {
            int colg = colbase + 64 * wn + 16 * ct + lrow;
            float b = bias[colg];
            #pragma unroll
            for (int rt = 0; rt < 8; ++rt) {
                long row = mbase + 128 * wm + 16 * rt + 4 * hi;
                #pragma unroll
                for (int r = 0; r < 4; ++r)
                    outp[(row + r) * 512 + colg] = acc[rt][ct][r] + b;
            }
        }
    }
}

// ---------------- K3: attention per (window, head), no barriers ----------------
__global__ __launch_bounds__(256)
void swa_attn(const __bf16* __restrict__ qk,   // [32768][1024] q 0-511 (scaled), k 512-1023
              const __bf16* __restrict__ vT,   // [256][8][64][128]
              __bf16* __restrict__ ctx)        // [32768][512]
{
    __shared__ __bf16 p_lds[4][32][136];

    const int bid = blockIdx.x;
    const int win = bid >> 3, h = bid & 7;
    const int tid = threadIdx.x;
    const int w = tid >> 6, lane = tid & 63;
    const int lrow = lane & 15, hi = lane >> 4;
    const long tokb = (long)win * 128;

    bf16x8 qa[2][2];
    #pragma unroll
    for (int rt = 0; rt < 2; ++rt)
        #pragma unroll
        for (int ks = 0; ks < 2; ++ks)
            qa[rt][ks] = *reinterpret_cast<const bf16x8*>(
                qk + (tokb + 32 * w + 16 * rt + lrow) * 1024 + h * 64 + ks * 32 + hi * 8);

    f32x4 s[2][8];
    #pragma unroll
    for (int rt = 0; rt < 2; ++rt)
        #pragma unroll
        for (int ct = 0; ct < 8; ++ct) s[rt][ct] = (f32x4){0.f, 0.f, 0.f, 0.f};
    #pragma unroll
    for (int ks = 0; ks < 2; ++ks) {
        #pragma unroll
        for (int ct = 0; ct < 8; ++ct) {
            bf16x8 kb = *reinterpret_cast<const bf16x8*>(
                qk + (tokb + 16 * ct + lrow) * 1024 + 512 + h * 64 + ks * 32 + hi * 8);
            s[0][ct] = MFMA16(qa[0][ks], kb, s[0][ct]);
            s[1][ct] = MFMA16(qa[1][ks], kb, s[1][ct]);
        }
    }

    float inv[2][4];
    #pragma unroll
    for (int rt = 0; rt < 2; ++rt) {
        #pragma unroll
        for (int r = 0; r < 4; ++r) {
            float m = s[rt][0][r];
            #pragma unroll
            for (int ct = 1; ct < 8; ++ct) m = fmaxf(m, s[rt][ct][r]);
            m = fmaxf(m, __shfl_xor(m, 1));
            m = fmaxf(m, __shfl_xor(m, 2));
            m = fmaxf(m, __shfl_xor(m, 4));
            m = fmaxf(m, __shfl_xor(m, 8));
            float sum = 0.f;
            #pragma unroll
            for (int ct = 0; ct < 8; ++ct) {
                float e = __expf(s[rt][ct][r] - m);
                sum += e;
                p_lds[w][16 * rt + 4 * hi + r][16 * ct + lrow] = (__bf16)e;
            }
            sum += __shfl_xor(sum, 1);
            sum += __shfl_xor(sum, 2);
            sum += __shfl_xor(sum, 4);
            sum += __shfl_xor(sum, 8);
            inv[rt][r] = 1.f / sum;
        }
    }

    f32x4 o[2][4];
    #pragma unroll
    for (int rt = 0; rt < 2; ++rt)
        #pragma unroll
        for (int ct = 0; ct < 4; ++ct) o[rt][ct] = (f32x4){0.f, 0.f, 0.f, 0.f};
    const __bf16* vb = vT + ((long)win * 8 + h) * 64 * 128;
    #pragma unroll
    for (int kt = 0; kt < 4; ++kt) {
        bf16x8 pa0 = *reinterpret_cast<const bf16x8*>(&p_lds[w][lrow][32 * kt + 8 * hi]);
        bf16x8 pa1 = *reinterpret_cast<const bf16x8*>(&p_lds[w][16 + lrow][32 * kt + 8 * hi]);
        #pragma unroll
        for (int ct = 0; ct < 4; ++ct) {
            bf16x8 vf = *reinterpret_cast<const bf16x8*>(
                vb + (16 * ct + lrow) * 128 + 32 * kt + 8 * hi);
            o[0][ct] = MFMA16(pa0, vf, o[0][ct]);
            o[1][ct] = MFMA16(pa1, vf, o[1][ct]);
        }
    }

    #pragma unroll
    for (int rt = 0; rt < 2; ++rt)
        #pragma unroll
        for (int ct = 0; ct < 4; ++ct)
            #pragma unroll
            for (int r = 0; r < 4; ++r) {
                long tok = tokb + 32 * w + 16 * rt + 4 * hi + r;
                ctx[tok * 512 + h * 64 + 16 * ct + lrow] =
                    (__bf16)(o[rt][ct][r] * inv[rt][r]);
            }
}

extern "C" void kernel_launch(void* const* d_in, const int* in_sizes, int n_in,
                              void* d_out, int out_size, void* d_ws, size_t ws_size,
                              hipStream_t stream)
{
    const float* x     = (const float*)d_in[0];
    const float* w_in  = (const float*)d_in[1];
    const float* b_in  = (const float*)d_in[2];
    const float* w_out = (const float*)d_in[3];
    const float* b_out = (const float*)d_in[4];

    // ws: [x_bf -> later ctx: 0, 33554432) [vT: 33554432, 67108864)
    //     [w_in_bf: 67108864, +1572864) [w_out_bf: 68681728, +524288)
    // qk scratch (67.1 MB bf16) lives in d_out until K4 overwrites it.
    char* ws = (char*)d_ws;
    __bf16* x_bf     = (__bf16*)(ws);
    __bf16* ctx      = (__bf16*)(ws);                  // reuses x_bf after K2
    __bf16* vT       = (__bf16*)(ws + 33554432);
    __bf16* w_in_bf  = (__bf16*)(ws + 67108864);
    __bf16* w_out_bf = (__bf16*)(ws + 68681728);
    __bf16* qk       = (__bf16*)d_out;

    convert_k<<<2048, 256, 0, stream>>>(x, w_in, w_out, x_bf, w_in_bf, w_out_bf);
    gemm256<0, 6><<<768, 512, 0, stream>>>(x_bf, w_in_bf, b_in, (void*)qk, vT);
    swa_attn<<<2048, 256, 0, stream>>>(qk, vT, ctx);
    gemm256<1, 2><<<256, 512, 0, stream>>>(ctx, w_out_bf, b_out, d_out, nullptr);
}

// Round 11
// 165.852 us; speedup vs baseline: 4.9378x; 4.9378x over previous
//
#include <hip/hip_runtime.h>

// SWA non-overlapping window MHA, MI355X gfx950.
// K1 convert fp32->bf16 (x, w_in, w_out)
// K2 QKV GEMM [32768x1536x512]: 256x256xBK32 dbuf-2 (64KiB LDS, 2 blocks/CU)
// K3 attention per (window, head) -> ctx bf16 [M][512]
// K4 out-proj GEMM [32768x512x512] + bias -> fp32 d_out (same template)

typedef __bf16 bf16x8 __attribute__((ext_vector_type(8)));
typedef __bf16 bf16x4 __attribute__((ext_vector_type(4)));
typedef float  f32x4  __attribute__((ext_vector_type(4)));

#define MFMA16(a, b, c) __builtin_amdgcn_mfma_f32_16x16x32_bf16((a), (b), (c), 0, 0, 0)
#define VMCNT_(n) asm volatile("s_waitcnt vmcnt(" #n ")" ::: "memory")
#define VMCNT(n) VMCNT_(n)
#define LGKM0() asm volatile("s_waitcnt lgkmcnt(0)" ::: "memory")

__device__ __forceinline__ void gload_lds16(const __bf16* g, void* l) {
    __builtin_amdgcn_global_load_lds(
        (const __attribute__((address_space(1))) unsigned int*)g,
        (__attribute__((address_space(3))) unsigned int*)l, 16, 0, 0);
}

// ---------------- K1: fp32 -> bf16 conversion ----------------
__device__ __forceinline__ void cvt8(const float* __restrict__ s,
                                     __bf16* __restrict__ d, long i) {
    const float4* s4 = reinterpret_cast<const float4*>(s);
    float4 a = s4[2 * i], b = s4[2 * i + 1];
    bf16x8 v;
    v[0] = (__bf16)a.x; v[1] = (__bf16)a.y; v[2] = (__bf16)a.z; v[3] = (__bf16)a.w;
    v[4] = (__bf16)b.x; v[5] = (__bf16)b.y; v[6] = (__bf16)b.z; v[7] = (__bf16)b.w;
    *reinterpret_cast<bf16x8*>(d + 8 * i) = v;
}

__global__ void convert_k(const float* __restrict__ x,
                          const float* __restrict__ w_in,
                          const float* __restrict__ w_out,
                          __bf16* __restrict__ x_bf,
                          __bf16* __restrict__ w_in_bf,
                          __bf16* __restrict__ w_out_bf)
{
    long i0 = (long)blockIdx.x * blockDim.x + threadIdx.x;
    long stride = (long)gridDim.x * blockDim.x;
    for (long i = i0; i < 16777216 / 8; i += stride) cvt8(x, x_bf, i);
    for (long i = i0; i < 786432 / 8;   i += stride) cvt8(w_in, w_in_bf, i);
    for (long i = i0; i < 262144 / 8;   i += stride) cvt8(w_out, w_out_bf, i);
}

// ---------------- K2/K4: 256x256xBK32 GEMM, dbuf-2, 2 blocks/CU ----------------
// LDS 64 KiB: A bufs at 0/16K, B bufs at 32K/48K; [256 rows][64 B] per buf.
// 4-slot swizzle (R7-verified): store chunk (tid&3)^((srow>>1)&3), read
// slot hi^((lrow>>1)&3). One vmcnt(0)+lgkm+barrier per K-tile; the drain
// stall is covered by the co-resident block (2/CU, launch_bounds(512,2),
// VGPR~104 < 128). A-frags read in 2 groups of 4 to keep regs at R5's level.
template<int EPI, int NN>
__global__ __launch_bounds__(512, 2)
void gemm256(const __bf16* __restrict__ A,
             const __bf16* __restrict__ Bw,
             const float* __restrict__ bias,
             void* __restrict__ Cq,
             __bf16* __restrict__ vT)
{
    __shared__ __align__(16) char smem[65536];

    const int nwg = gridDim.x;
    const int chunk = nwg >> 3;                       // nwg % 8 == 0
    const int bid = blockIdx.x;
    const int wg = (bid & 7) * chunk + (bid >> 3);    // XCD-contiguous chunks
    const int nidx = wg % NN;
    const int midx = wg / NN;
    const long mbase = (long)midx * 256;
    const int colbase = nidx * 256;

    const int tid = threadIdx.x;
    const int w = tid >> 6, lane = tid & 63;
    const int lrow = lane & 15, hi = lane >> 4;
    const int wm = w >> 2, wn = w & 3;                // wave tile 128x64

    // staging: srow = tid>>2 covers 128 rows/gload (2 gloads per operand);
    // 16B k-chunk pre-swizzled so LDS[row][s] = global chunk s^((row>>1)&3)
    const int srow = tid >> 2;
    const int kchunk = (tid & 3) ^ ((srow >> 1) & 3);
    const __bf16* PA = A  + (mbase + srow) * 512 + kchunk * 8;
    const __bf16* PB = Bw + ((long)colbase + srow) * 512 + kchunk * 8;
    // read-side: slot = hi ^ ((lrow>>1)&3) (frag rows are 16-aligned)
    const int rd16 = (hi ^ ((lrow >> 1) & 3)) << 4;

    auto stage = [&](int t) {                         // 4 gload16/thread = 1 K-tile
        char* Ab = smem + (t & 1) * 16384;
        char* Bb = smem + 32768 + (t & 1) * 16384;
        const int ko = t * 32;
        gload_lds16(PA + ko,             Ab + w * 1024);
        gload_lds16(PA + 128 * 512 + ko, Ab + 8192 + w * 1024);
        gload_lds16(PB + ko,             Bb + w * 1024);
        gload_lds16(PB + 128 * 512 + ko, Bb + 8192 + w * 1024);
    };

    f32x4 acc[8][4];
    #pragma unroll
    for (int rt = 0; rt < 8; ++rt)
        #pragma unroll
        for (int ct = 0; ct < 4; ++ct) acc[rt][ct] = (f32x4){0.f, 0.f, 0.f, 0.f};

    stage(0);

    #pragma unroll 1
    for (int t = 0; t < 16; ++t) {
        VMCNT(0);                                     // tile t landed
        LGKM0();                                      // my reads of buf t&1 done
        __builtin_amdgcn_s_barrier();                 // all waves done with buf t&1
        if (t < 15) stage(t + 1);
        const char* Ab = smem + (t & 1) * 16384;
        const char* Bb = smem + 32768 + (t & 1) * 16384;
        bf16x8 af[4], bfr[4];
        #pragma unroll
        for (int ct = 0; ct < 4; ++ct)
            bfr[ct] = *reinterpret_cast<const bf16x8*>(
                Bb + (64 * wn + 16 * ct + lrow) * 64 + rd16);
        // group 1: wave-tile rows 0-63
        #pragma unroll
        for (int i = 0; i < 4; ++i)
            af[i] = *reinterpret_cast<const bf16x8*>(
                Ab + (128 * wm + 16 * i + lrow) * 64 + rd16);
        __builtin_amdgcn_s_setprio(1);
        #pragma unroll
        for (int i = 0; i < 4; ++i)
            #pragma unroll
            for (int ct = 0; ct < 4; ++ct)
                acc[i][ct] = MFMA16(af[i], bfr[ct], acc[i][ct]);
        __builtin_amdgcn_s_setprio(0);
        // group 2: wave-tile rows 64-127
        #pragma unroll
        for (int i = 0; i < 4; ++i)
            af[i] = *reinterpret_cast<const bf16x8*>(
                Ab + (128 * wm + 64 + 16 * i + lrow) * 64 + rd16);
        __builtin_amdgcn_s_setprio(1);
        #pragma unroll
        for (int i = 0; i < 4; ++i)
            #pragma unroll
            for (int ct = 0; ct < 4; ++ct)
                acc[4 + i][ct] = MFMA16(af[i], bfr[ct], acc[4 + i][ct]);
        __builtin_amdgcn_s_setprio(0);
    }

    // ---- epilogue: direct stores (dense per-block footprint) ----
    if (EPI == 0) {
        if (colbase < 1024) {
            const float scale = (colbase < 512) ? 0.125f : 1.0f;
            __bf16* qk = (__bf16*)Cq;
            #pragma unroll
            for (int ct = 0; ct < 4; ++ct) {
                int colg = colbase + 64 * wn + 16 * ct + lrow;
                float b = bias[colg];
                #pragma unroll
                for (int rt = 0; rt < 8; ++rt) {
                    long row = mbase + 128 * wm + 16 * rt + 4 * hi;
                    #pragma unroll
                    for (int r = 0; r < 4; ++r)
                        qk[(row + r) * 1024 + colg] = (__bf16)((acc[rt][ct][r] + b) * scale);
                }
            }
        } else {
            // v -> vT[win][h][d][tok], 4 consecutive toks packed (8B stores)
            #pragma unroll
            for (int ct = 0; ct < 4; ++ct) {
                int colg = colbase + 64 * wn + 16 * ct + lrow;
                float b = bias[colg];
                int e2 = colg - 1024;
                int h = e2 >> 6, d = e2 & 63;
                #pragma unroll
                for (int rt = 0; rt < 8; ++rt) {
                    long row = mbase + 128 * wm + 16 * rt + 4 * hi;
                    int win = (int)(row >> 7), tok0 = (int)(row & 127);
                    bf16x4 pk;
                    pk[0] = (__bf16)(acc[rt][ct][0] + b);
                    pk[1] = (__bf16)(acc[rt][ct][1] + b);
                    pk[2] = (__bf16)(acc[rt][ct][2] + b);
                    pk[3] = (__bf16)(acc[rt][ct][3] + b);
                    *reinterpret_cast<bf16x4*>(
                        vT + (((long)win * 8 + h) * 64 + d) * 128 + tok0) = pk;
                }
            }
        }
    } else {
        float* outp = (float*)Cq;
        #pragma unroll
        for (int ct = 0; ct < 4; ++ct) {
            int colg = colbase + 64 * wn + 16 * ct + lrow;
            float b = bias[colg];
            #pragma unroll
            for (int rt = 0; rt < 8; ++rt) {
                long row = mbase + 128 * wm + 16 * rt + 4 * hi;
                #pragma unroll
                for (int r = 0; r < 4; ++r)
                    outp[(row + r) * 512 + colg] = acc[rt][ct][r] + b;
            }
        }
    }
}

// ---------------- K3: attention per (window, head), no barriers ----------------
__global__ __launch_bounds__(256)
void swa_attn(const __bf16* __restrict__ qk,   // [32768][1024] q 0-511 (scaled), k 512-1023
              const __bf16* __restrict__ vT,   // [256][8][64][128]
              __bf16* __restrict__ ctx)        // [32768][512]
{
    __shared__ __bf16 p_lds[4][32][136];

    const int bid = blockIdx.x;
    const int win = bid >> 3, h = bid & 7;
    const int tid = threadIdx.x;
    const int w = tid >> 6, lane = tid & 63;
    const int lrow = lane & 15, hi = lane >> 4;
    const long tokb = (long)win * 128;

    bf16x8 qa[2][2];
    #pragma unroll
    for (int rt = 0; rt < 2; ++rt)
        #pragma unroll
        for (int ks = 0; ks < 2; ++ks)
            qa[rt][ks] = *reinterpret_cast<const bf16x8*>(
                qk + (tokb + 32 * w + 16 * rt + lrow) * 1024 + h * 64 + ks * 32 + hi * 8);

    f32x4 s[2][8];
    #pragma unroll
    for (int rt = 0; rt < 2; ++rt)
        #pragma unroll
        for (int ct = 0; ct < 8; ++ct) s[rt][ct] = (f32x4){0.f, 0.f, 0.f, 0.f};
    #pragma unroll
    for (int ks = 0; ks < 2; ++ks) {
        #pragma unroll
        for (int ct = 0; ct < 8; ++ct) {
            bf16x8 kb = *reinterpret_cast<const bf16x8*>(
                qk + (tokb + 16 * ct + lrow) * 1024 + 512 + h * 64 + ks * 32 + hi * 8);
            s[0][ct] = MFMA16(qa[0][ks], kb, s[0][ct]);
            s[1][ct] = MFMA16(qa[1][ks], kb, s[1][ct]);
        }
    }

    float inv[2][4];
    #pragma unroll
    for (int rt = 0; rt < 2; ++rt) {
        #pragma unroll
        for (int r = 0; r < 4; ++r) {
            float m = s[rt][0][r];
            #pragma unroll
            for (int ct = 1; ct < 8; ++ct) m = fmaxf(m, s[rt][ct][r]);
            m = fmaxf(m, __shfl_xor(m, 1));
            m = fmaxf(m, __shfl_xor(m, 2));
            m = fmaxf(m, __shfl_xor(m, 4));
            m = fmaxf(m, __shfl_xor(m, 8));
            float sum = 0.f;
            #pragma unroll
            for (int ct = 0; ct < 8; ++ct) {
                float e = __expf(s[rt][ct][r] - m);
                sum += e;
                p_lds[w][16 * rt + 4 * hi + r][16 * ct + lrow] = (__bf16)e;
            }
            sum += __shfl_xor(sum, 1);
            sum += __shfl_xor(sum, 2);
            sum += __shfl_xor(sum, 4);
            sum += __shfl_xor(sum, 8);
            inv[rt][r] = 1.f / sum;
        }
    }

    f32x4 o[2][4];
    #pragma unroll
    for (int rt = 0; rt < 2; ++rt)
        #pragma unroll
        for (int ct = 0; ct < 4; ++ct) o[rt][ct] = (f32x4){0.f, 0.f, 0.f, 0.f};
    const __bf16* vb = vT + ((long)win * 8 + h) * 64 * 128;
    #pragma unroll
    for (int kt = 0; kt < 4; ++kt) {
        bf16x8 pa0 = *reinterpret_cast<const bf16x8*>(&p_lds[w][lrow][32 * kt + 8 * hi]);
        bf16x8 pa1 = *reinterpret_cast<const bf16x8*>(&p_lds[w][16 + lrow][32 * kt + 8 * hi]);
        #pragma unroll
        for (int ct = 0; ct < 4; ++ct) {
            bf16x8 vf = *reinterpret_cast<const bf16x8*>(
                vb + (16 * ct + lrow) * 128 + 32 * kt + 8 * hi);
            o[0][ct] = MFMA16(pa0, vf, o[0][ct]);
            o[1][ct] = MFMA16(pa1, vf, o[1][ct]);
        }
    }

    #pragma unroll
    for (int rt = 0; rt < 2; ++rt)
        #pragma unroll
        for (int ct = 0; ct < 4; ++ct)
            #pragma unroll
            for (int r = 0; r < 4; ++r) {
                long tok = tokb + 32 * w + 16 * rt + 4 * hi + r;
                ctx[tok * 512 + h * 64 + 16 * ct + lrow] =
                    (__bf16)(o[rt][ct][r] * inv[rt][r]);
            }
}

extern "C" void kernel_launch(void* const* d_in, const int* in_sizes, int n_in,
                              void* d_out, int out_size, void* d_ws, size_t ws_size,
                              hipStream_t stream)
{
    const float* x     = (const float*)d_in[0];
    const float* w_in  = (const float*)d_in[1];
    const float* b_in  = (const float*)d_in[2];
    const float* w_out = (const float*)d_in[3];
    const float* b_out = (const float*)d_in[4];

    // ws: [x_bf -> later ctx: 0, 33554432) [vT: 33554432, 67108864)
    //     [w_in_bf: 67108864, +1572864) [w_out_bf: 68681728, +524288)
    // qk scratch (67.1 MB bf16) lives in d_out until K4 overwrites it.
    char* ws = (char*)d_ws;
    __bf16* x_bf     = (__bf16*)(ws);
    __bf16* ctx      = (__bf16*)(ws);                  // reuses x_bf after K2
    __bf16* vT       = (__bf16*)(ws + 33554432);
    __bf16* w_in_bf  = (__bf16*)(ws + 67108864);
    __bf16* w_out_bf = (__bf16*)(ws + 68681728);
    __bf16* qk       = (__bf16*)d_out;

    convert_k<<<2048, 256, 0, stream>>>(x, w_in, w_out, x_bf, w_in_bf, w_out_bf);
    gemm256<0, 6><<<768, 512, 0, stream>>>(x_bf, w_in_bf, b_in, (void*)qk, vT);
    swa_attn<<<2048, 256, 0, stream>>>(qk, vT, ctx);
    gemm256<1, 2><<<256, 512, 0, stream>>>(ctx, w_out_bf, b_out, d_out, nullptr);
}

// Round 13
// 160.037 us; speedup vs baseline: 5.1172x; 1.0363x over previous
//
#include <hip/hip_runtime.h>

// SWA non-overlapping window MHA, MI355X gfx950.
// K1 convert fp32->bf16 (x, w_in, w_out)
// K2 QKV GEMM [32768x1536x512]: 256x128xBK32, ring-3 (72KiB), R8-law loop + R7 swizzle
// K3 attention per (window, head) -> ctx bf16 [M][512]
// K4 out-proj GEMM [32768x512x512] + bias -> fp32 d_out (same template)

typedef __bf16 bf16x8 __attribute__((ext_vector_type(8)));
typedef __bf16 bf16x4 __attribute__((ext_vector_type(4)));
typedef float  f32x4  __attribute__((ext_vector_type(4)));

#define MFMA16(a, b, c) __builtin_amdgcn_mfma_f32_16x16x32_bf16((a), (b), (c), 0, 0, 0)
#define VMCNT_(n) asm volatile("s_waitcnt vmcnt(" #n ")" ::: "memory")
#define VMCNT(n) VMCNT_(n)
#define LGKM0() asm volatile("s_waitcnt lgkmcnt(0)" ::: "memory")
#define BAR() __builtin_amdgcn_s_barrier()

__device__ __forceinline__ void gload_lds16(const __bf16* g, void* l) {
    __builtin_amdgcn_global_load_lds(
        (const __attribute__((address_space(1))) unsigned int*)g,
        (__attribute__((address_space(3))) unsigned int*)l, 16, 0, 0);
}

// ---------------- K1: fp32 -> bf16 conversion ----------------
__device__ __forceinline__ void cvt8(const float* __restrict__ s,
                                     __bf16* __restrict__ d, long i) {
    const float4* s4 = reinterpret_cast<const float4*>(s);
    float4 a = s4[2 * i], b = s4[2 * i + 1];
    bf16x8 v;
    v[0] = (__bf16)a.x; v[1] = (__bf16)a.y; v[2] = (__bf16)a.z; v[3] = (__bf16)a.w;
    v[4] = (__bf16)b.x; v[5] = (__bf16)b.y; v[6] = (__bf16)b.z; v[7] = (__bf16)b.w;
    *reinterpret_cast<bf16x8*>(d + 8 * i) = v;
}

__global__ void convert_k(const float* __restrict__ x,
                          const float* __restrict__ w_in,
                          const float* __restrict__ w_out,
                          __bf16* __restrict__ x_bf,
                          __bf16* __restrict__ w_in_bf,
                          __bf16* __restrict__ w_out_bf)
{
    long i0 = (long)blockIdx.x * blockDim.x + threadIdx.x;
    long stride = (long)gridDim.x * blockDim.x;
    for (long i = i0; i < 16777216 / 8; i += stride) cvt8(x, x_bf, i);
    for (long i = i0; i < 786432 / 8;   i += stride) cvt8(w_in, w_in_bf, i);
    for (long i = i0; i < 262144 / 8;   i += stride) cvt8(w_out, w_out_bf, i);
}

// ---------------- K2/K4: 256x128xBK32 GEMM, ring-3, 2 blocks/CU ----------------
// LDS 72 KiB: slot s at s*24576 {A [256 rows][64 B], B [128 rows][64 B] at +16384}.
// Loop (R8-verified law discipline): iter t: VMCNT(6) [tile t landed, t+1 in
// flight], LGKM0, barrier, stage(t+2 -> slot (t+2)%3), 12 ds_read_b128, 32 MFMA.
// Ring-3 makes WAR trivially safe (stage target = slot read at iter t-1, whose
// reads all retired at this iter's lgkm0+barrier). R7 4-slot swizzle on reads.
// Block 256 thr = 4 waves, wave grid 2Mx2N, wave tile 128x64, acc[8][4].
template<int EPI, int NN>
__global__ __launch_bounds__(256, 2)
void gemmT(const __bf16* __restrict__ A,
           const __bf16* __restrict__ Bw,
           const float* __restrict__ bias,
           void* __restrict__ Cq,
           __bf16* __restrict__ vT)
{
    __shared__ __align__(16) char smem[73728];

    const int nwg = gridDim.x;
    const int chunk = nwg >> 3;                       // nwg % 8 == 0
    const int bid = blockIdx.x;
    const int wg = (bid & 7) * chunk + (bid >> 3);    // XCD-contiguous chunks
    const int nidx = wg % NN;
    const int midx = wg / NN;
    const long mbase = (long)midx * 256;
    const int colbase = nidx * 128;

    const int tid = threadIdx.x;
    const int w = tid >> 6, lane = tid & 63;
    const int lrow = lane & 15, hi = lane >> 4;
    const int wm = w >> 1, wn = w & 1;                // wave tile 128 rows x 64 cols

    // staging: srow = tid>>2 (0..63 per instr), 16B chunk pre-swizzled:
    // LDS[row][s] holds global chunk s ^ ((row>>1)&3)
    const int srow = tid >> 2;
    const int kchunk = (tid & 3) ^ ((srow >> 1) & 3);
    const __bf16* PA = A  + (mbase + srow) * 512 + kchunk * 8;
    const __bf16* PB = Bw + ((long)colbase + srow) * 512 + kchunk * 8;
    // read-side swizzle: slot = hi ^ ((lrow>>1)&3)
    const int rd16 = (hi ^ ((lrow >> 1) & 3)) << 4;

    auto stage = [&](int t, int slot) {               // 6 gload16/thread = 1 K-tile
        char* Ab = smem + slot * 24576;
        char* Bb = Ab + 16384;
        const int ko = t * 32;
        #pragma unroll
        for (int j = 0; j < 4; ++j)
            gload_lds16(PA + (64 * j) * 512 + ko, Ab + j * 4096 + w * 1024);
        #pragma unroll
        for (int j = 0; j < 2; ++j)
            gload_lds16(PB + (64 * j) * 512 + ko, Bb + j * 4096 + w * 1024);
    };

    f32x4 acc[8][4];
    #pragma unroll
    for (int rt = 0; rt < 8; ++rt)
        #pragma unroll
        for (int ct = 0; ct < 4; ++ct) acc[rt][ct] = (f32x4){0.f, 0.f, 0.f, 0.f};

    // prologue: tiles 0,1 -> slots 0,1 (12 loads/thread in flight)
    stage(0, 0); stage(1, 1);

    int cs = 0;                                       // t % 3
    int ss = 2;                                       // (t+2) % 3
    #pragma unroll 1
    for (int t = 0; t < 16; ++t) {
        if (t < 15) { VMCNT(6); } else { VMCNT(0); }
        LGKM0();
        BAR();
        if (t < 14) stage(t + 2, ss);
        const char* Ab = smem + cs * 24576;
        const char* Bb = Ab + 16384;
        bf16x8 af[4], bfr[4];
        #pragma unroll
        for (int ct = 0; ct < 4; ++ct)
            bfr[ct] = *reinterpret_cast<const bf16x8*>(
                Bb + (64 * wn + 16 * ct + lrow) * 64 + rd16);
        #pragma unroll
        for (int i = 0; i < 4; ++i)
            af[i] = *reinterpret_cast<const bf16x8*>(
                Ab + (128 * wm + 16 * i + lrow) * 64 + rd16);
        __builtin_amdgcn_s_setprio(1);
        #pragma unroll
        for (int i = 0; i < 4; ++i)
            #pragma unroll
            for (int ct = 0; ct < 4; ++ct)
                acc[i][ct] = MFMA16(af[i], bfr[ct], acc[i][ct]);
        __builtin_amdgcn_s_setprio(0);
        #pragma unroll
        for (int i = 0; i < 4; ++i)
            af[i] = *reinterpret_cast<const bf16x8*>(
                Ab + (128 * wm + 64 + 16 * i + lrow) * 64 + rd16);
        __builtin_amdgcn_s_setprio(1);
        #pragma unroll
        for (int i = 0; i < 4; ++i)
            #pragma unroll
            for (int ct = 0; ct < 4; ++ct)
                acc[4 + i][ct] = MFMA16(af[i], bfr[ct], acc[4 + i][ct]);
        __builtin_amdgcn_s_setprio(0);
        cs = (cs == 2) ? 0 : cs + 1;
        ss = (ss == 2) ? 0 : ss + 1;
    }
    LGKM0();
    BAR();                                            // ring reads done; smem reusable

    // ---- epilogue ----
    if (EPI == 0) {
        if (colbase < 1024) {
            // q/k: LDS [256 row][128 col] bf16 pitch 256B, chunk ^= row&15
            const float scale = (colbase < 512) ? 0.125f : 1.0f;
            __bf16* qk = (__bf16*)Cq;
            #pragma unroll
            for (int ct = 0; ct < 4; ++ct) {
                int col = 64 * wn + 16 * ct + lrow;
                float b = bias[colbase + col];
                #pragma unroll
                for (int rt = 0; rt < 8; ++rt)
                    #pragma unroll
                    for (int r = 0; r < 4; ++r) {
                        int row = 128 * wm + 16 * rt + 4 * hi + r;
                        *reinterpret_cast<__bf16*>(
                            smem + row * 256 + ((col * 2) ^ ((row & 15) << 4))) =
                            (__bf16)((acc[rt][ct][r] + b) * scale);
                    }
            }
            LGKM0();
            BAR();
            #pragma unroll
            for (int i = 0; i < 16; ++i) {
                int row = 16 * i + (tid >> 4);
                int slot = (tid & 15) ^ (tid >> 4);
                bf16x8 v = *reinterpret_cast<const bf16x8*>(smem + row * 256 + slot * 16);
                *reinterpret_cast<bf16x8*>(
                    qk + (mbase + row) * 1024 + colbase + (tid & 15) * 8) = v;
            }
        } else {
            // v: LDS transposed [128 e][256 tok] bf16 pitch 512B, chunk ^= e&15
            #pragma unroll
            for (int ct = 0; ct < 4; ++ct) {
                int e = 64 * wn + 16 * ct + lrow;
                float b = bias[colbase + e];
                #pragma unroll
                for (int rt = 0; rt < 8; ++rt) {
                    int tok0 = 128 * wm + 16 * rt + 4 * hi;
                    bf16x4 pk;
                    pk[0] = (__bf16)(acc[rt][ct][0] + b);
                    pk[1] = (__bf16)(acc[rt][ct][1] + b);
                    pk[2] = (__bf16)(acc[rt][ct][2] + b);
                    pk[3] = (__bf16)(acc[rt][ct][3] + b);
                    *reinterpret_cast<bf16x4*>(
                        smem + e * 512 + ((tok0 * 2) ^ ((e & 15) << 4))) = pk;
                }
            }
            LGKM0();
            BAR();
            #pragma unroll
            for (int i = 0; i < 16; ++i) {
                int e = 8 * i + (tid >> 5);
                int gch = tid & 31;                   // tok chunk (8 toks)
                int slot = gch ^ (e & 15);
                bf16x8 v = *reinterpret_cast<const bf16x8*>(smem + e * 512 + slot * 16);
                long win = 2 * midx + (gch >> 4);
                *reinterpret_cast<bf16x8*>(
                    vT + (win * 512 + (colbase - 1024 + e)) * 128 + (gch & 15) * 8) = v;
            }
        }
    } else {
        // fp32 direct: 16 lanes x 4B consecutive = full 64B sectors
        float* outp = (float*)Cq;
        #pragma unroll
        for (int ct = 0; ct < 4; ++ct) {
            int colg = colbase + 64 * wn + 16 * ct + lrow;
            float b = bias[colg];
            #pragma unroll
            for (int rt = 0; rt < 8; ++rt) {
                long row = mbase + 128 * wm + 16 * rt + 4 * hi;
                #pragma unroll
                for (int r = 0; r < 4; ++r)
                    outp[(row + r) * 512 + colg] = acc[rt][ct][r] + b;
            }
        }
    }
}

// ---------------- K3: attention per (window, head), no barriers ----------------
__global__ __launch_bounds__(256)
void swa_attn(const __bf16* __restrict__ qk,   // [32768][1024] q 0-511 (scaled), k 512-1023
              const __bf16* __restrict__ vT,   // [256][512][128] = [win][h*64+d][tok]
              __bf16* __restrict__ ctx)        // [32768][512]
{
    __shared__ __bf16 p_lds[4][32][136];

    const int bid = blockIdx.x;
    const int win = bid >> 3, h = bid & 7;
    const int tid = threadIdx.x;
    const int w = tid >> 6, lane = tid & 63;
    const int lrow = lane & 15, hi = lane >> 4;
    const long tokb = (long)win * 128;

    bf16x8 qa[2][2];
    #pragma unroll
    for (int rt = 0; rt < 2; ++rt)
        #pragma unroll
        for (int ks = 0; ks < 2; ++ks)
            qa[rt][ks] = *reinterpret_cast<const bf16x8*>(
                qk + (tokb + 32 * w + 16 * rt + lrow) * 1024 + h * 64 + ks * 32 + hi * 8);

    f32x4 s[2][8];
    #pragma unroll
    for (int rt = 0; rt < 2; ++rt)
        #pragma unroll
        for (int ct = 0; ct < 8; ++ct) s[rt][ct] = (f32x4){0.f, 0.f, 0.f, 0.f};
    #pragma unroll
    for (int ks = 0; ks < 2; ++ks) {
        #pragma unroll
        for (int ct = 0; ct < 8; ++ct) {
            bf16x8 kb = *reinterpret_cast<const bf16x8*>(
                qk + (tokb + 16 * ct + lrow) * 1024 + 512 + h * 64 + ks * 32 + hi * 8);
            s[0][ct] = MFMA16(qa[0][ks], kb, s[0][ct]);
            s[1][ct] = MFMA16(qa[1][ks], kb, s[1][ct]);
        }
    }

    float inv[2][4];
    #pragma unroll
    for (int rt = 0; rt < 2; ++rt) {
        #pragma unroll
        for (int r = 0; r < 4; ++r) {
            float m = s[rt][0][r];
            #pragma unroll
            for (int ct = 1; ct < 8; ++ct) m = fmaxf(m, s[rt][ct][r]);
            m = fmaxf(m, __shfl_xor(m, 1));
            m = fmaxf(m, __shfl_xor(m, 2));
            m = fmaxf(m, __shfl_xor(m, 4));
            m = fmaxf(m, __shfl_xor(m, 8));
            float sum = 0.f;
            #pragma unroll
            for (int ct = 0; ct < 8; ++ct) {
                float e = __expf(s[rt][ct][r] - m);
                sum += e;
                p_lds[w][16 * rt + 4 * hi + r][16 * ct + lrow] = (__bf16)e;
            }
            sum += __shfl_xor(sum, 1);
            sum += __shfl_xor(sum, 2);
            sum += __shfl_xor(sum, 4);
            sum += __shfl_xor(sum, 8);
            inv[rt][r] = 1.f / sum;
        }
    }

    f32x4 o[2][4];
    #pragma unroll
    for (int rt = 0; rt < 2; ++rt)
        #pragma unroll
        for (int ct = 0; ct < 4; ++ct) o[rt][ct] = (f32x4){0.f, 0.f, 0.f, 0.f};
    const __bf16* vb = vT + (long)win * 512 * 128 + (long)h * 64 * 128;
    #pragma unroll
    for (int kt = 0; kt < 4; ++kt) {
        bf16x8 pa0 = *reinterpret_cast<const bf16x8*>(&p_lds[w][lrow][32 * kt + 8 * hi]);
        bf16x8 pa1 = *reinterpret_cast<const bf16x8*>(&p_lds[w][16 + lrow][32 * kt + 8 * hi]);
        #pragma unroll
        for (int ct = 0; ct < 4; ++ct) {
            bf16x8 vf = *reinterpret_cast<const bf16x8*>(
                vb + (16 * ct + lrow) * 128 + 32 * kt + 8 * hi);
            o[0][ct] = MFMA16(pa0, vf, o[0][ct]);
            o[1][ct] = MFMA16(pa1, vf, o[1][ct]);
        }
    }

    #pragma unroll
    for (int rt = 0; rt < 2; ++rt)
        #pragma unroll
        for (int ct = 0; ct < 4; ++ct)
            #pragma unroll
            for (int r = 0; r < 4; ++r) {
                long tok = tokb + 32 * w + 16 * rt + 4 * hi + r;
                ctx[tok * 512 + h * 64 + 16 * ct + lrow] =
                    (__bf16)(o[rt][ct][r] * inv[rt][r]);
            }
}

extern "C" void kernel_launch(void* const* d_in, const int* in_sizes, int n_in,
                              void* d_out, int out_size, void* d_ws, size_t ws_size,
                              hipStream_t stream)
{
    const float* x     = (const float*)d_in[0];
    const float* w_in  = (const float*)d_in[1];
    const float* b_in  = (const float*)d_in[2];
    const float* w_out = (const float*)d_in[3];
    const float* b_out = (const float*)d_in[4];

    // ws: [x_bf -> later ctx: 0, 33554432) [vT: 33554432, 67108864)
    //     [w_in_bf: 67108864, +1572864) [w_out_bf: 68681728, +524288)
    // qk scratch (67.1 MB bf16) lives in d_out until K4 overwrites it.
    char* ws = (char*)d_ws;
    __bf16* x_bf     = (__bf16*)(ws);
    __bf16* ctx      = (__bf16*)(ws);                  // reuses x_bf after K2
    __bf16* vT       = (__bf16*)(ws + 33554432);
    __bf16* w_in_bf  = (__bf16*)(ws + 67108864);
    __bf16* w_out_bf = (__bf16*)(ws + 68681728);
    __bf16* qk       = (__bf16*)d_out;

    convert_k<<<2048, 256, 0, stream>>>(x, w_in, w_out, x_bf, w_in_bf, w_out_bf);
    gemmT<0, 12><<<1536, 256, 0, stream>>>(x_bf, w_in_bf, b_in, (void*)qk, vT);
    swa_attn<<<2048, 256, 0, stream>>>(qk, vT, ctx);
    gemmT<1, 4><<<512, 256, 0, stream>>>(ctx, w_out_bf, b_out, d_out, nullptr);
}